// Round 1
// baseline (215.634 us; speedup 1.0000x reference)
//
#include <hip/hip_runtime.h>

// TAM fused kernel: pool -> G(softmax kern) + L(sigmoid gate) -> gated
// depthwise temporal conv -> transposed write.
// Shapes (hardcoded per reference): C=12, T=10, H*W=28, K=3, n=in_sizes[0]/3360.

#define CC 12
#define TT 10
#define HWS 28
#define KK 3
#define CT (CC*TT)            // 120
#define SAMPLE (CC*TT*HWS)    // 3360 floats per sample (13.44 KB)
#define SAMPLE4 (SAMPLE/4)    // 840 float4
#define CHW4 (CC*HWS/4)       // 84 float4 per t-chunk
#define HW4 (HWS/4)           // 7 float4 per (c)
#define EPSF 1e-5f

__global__ __launch_bounds__(256) void tam_kernel(
    const float* __restrict__ x,
    const float* __restrict__ w_g1,
    const float* __restrict__ g1_gamma, const float* __restrict__ g1_beta,
    const float* __restrict__ g1_mean,  const float* __restrict__ g1_var,
    const float* __restrict__ w_g2,
    const float* __restrict__ w_l1,
    const float* __restrict__ l1_gamma, const float* __restrict__ l1_beta,
    const float* __restrict__ l1_mean,  const float* __restrict__ l1_var,
    const float* __restrict__ w_l2,
    float* __restrict__ out)
{
    __shared__ float sx[SAMPLE];     // x[c][t][s]
    __shared__ float spool[CT];      // pooled[c][t]
    __shared__ float skern[CC*KK];   // softmax kernel per (c,k)
    __shared__ float sa1[3*TT];      // L-branch hidden
    __shared__ float sact[CT];       // sigmoid gate per (c,t)

    const int n  = blockIdx.x;
    const int tid = threadIdx.x;

    // ---- phase 1: stage sample into LDS (float4, fully coalesced) ----
    const float4* xg  = reinterpret_cast<const float4*>(x + (size_t)n * SAMPLE);
    float4* sx4 = reinterpret_cast<float4*>(sx);
    #pragma unroll
    for (int v = tid; v < SAMPLE4; v += 256) sx4[v] = xg[v];
    __syncthreads();

    // ---- phase 2: spatial mean -> pooled[c][t] (120 threads) ----
    if (tid < CT) {
        const float* row = sx + tid * HWS;
        float s = 0.f;
        #pragma unroll
        for (int i = 0; i < HWS; ++i) s += row[i];
        spool[tid] = s * (1.0f / 28.0f);
    }
    __syncthreads();

    // ---- phase 3a (wave 0, tid<12): G branch -> skern[c][k] ----
    if (tid < CC) {
        const int c = tid;
        float z[2 * TT];
        #pragma unroll
        for (int j = 0; j < 2 * TT; ++j) {
            float s = 0.f;
            #pragma unroll
            for (int t = 0; t < TT; ++t) s += spool[c * TT + t] * w_g1[j * TT + t];
            s = (s - g1_mean[j]) * rsqrtf(g1_var[j] + EPSF) * g1_gamma[j] + g1_beta[j];
            z[j] = fmaxf(s, 0.f);
        }
        float sc[KK];
        float m = -1e30f;
        #pragma unroll
        for (int k = 0; k < KK; ++k) {
            float s = 0.f;
            #pragma unroll
            for (int j = 0; j < 2 * TT; ++j) s += z[j] * w_g2[k * 2 * TT + j];
            sc[k] = s;
            m = fmaxf(m, s);
        }
        float den = 0.f;
        #pragma unroll
        for (int k = 0; k < KK; ++k) { sc[k] = __expf(sc[k] - m); den += sc[k]; }
        const float r = 1.0f / den;
        #pragma unroll
        for (int k = 0; k < KK; ++k) skern[c * KK + k] = sc[k] * r;
    }

    // ---- phase 3b (wave 1, tid 64..93): L conv1 + BN + ReLU -> sa1[m][t] ----
    if (tid >= 64 && tid < 64 + 3 * TT) {
        const int idx = tid - 64;
        const int m = idx / TT, t = idx % TT;
        float s = 0.f;
        #pragma unroll
        for (int c = 0; c < CC; ++c) {
            #pragma unroll
            for (int k = 0; k < KK; ++k) {
                const int tt2 = t + k - 1;
                if (tt2 >= 0 && tt2 < TT)
                    s += spool[c * TT + tt2] * w_l1[(m * CC + c) * KK + k];
            }
        }
        s = (s - l1_mean[m]) * rsqrtf(l1_var[m] + EPSF) * l1_gamma[m] + l1_beta[m];
        sa1[idx] = fmaxf(s, 0.f);
    }
    __syncthreads();

    // ---- phase 4: L conv2 (1x1) + sigmoid -> sact[c][t] (120 threads) ----
    if (tid < CT) {
        const int c = tid / TT, t = tid % TT;
        float s = 0.f;
        #pragma unroll
        for (int m = 0; m < 3; ++m) s += sa1[m * TT + t] * w_l2[c * 3 + m];
        sact[tid] = 1.0f / (1.0f + __expf(-s));
    }
    __syncthreads();

    // ---- phase 5: gated temporal conv, transposed write ----
    // out[(n*T + t)*C*HW + c*HW + s] = sum_j kern[c][j] * act[c][t+j-1] * x[c][t+j-1][s]
    // Per-sample output region is contiguous: out + n*SAMPLE, offset t*C*HW + c*HW + s.
    float4* og4 = reinterpret_cast<float4*>(out + (size_t)n * SAMPLE);
    #pragma unroll
    for (int v = tid; v < SAMPLE4; v += 256) {
        const int t   = v / CHW4;       // 0..9
        const int rem = v % CHW4;       // 0..83
        const int c   = rem / HW4;      // 0..11
        const int s4  = (rem % HW4) * 4;
        const float* base = sx + c * (TT * HWS) + s4;
        const float k0 = skern[c * KK + 0];
        const float k1 = skern[c * KK + 1];
        const float k2 = skern[c * KK + 2];
        float4 acc = make_float4(0.f, 0.f, 0.f, 0.f);
        if (t > 0) {
            const float a = sact[c * TT + (t - 1)] * k0;
            const float4 xv = *reinterpret_cast<const float4*>(base + (t - 1) * HWS);
            acc.x += a * xv.x; acc.y += a * xv.y; acc.z += a * xv.z; acc.w += a * xv.w;
        }
        {
            const float a = sact[c * TT + t] * k1;
            const float4 xv = *reinterpret_cast<const float4*>(base + t * HWS);
            acc.x += a * xv.x; acc.y += a * xv.y; acc.z += a * xv.z; acc.w += a * xv.w;
        }
        if (t < TT - 1) {
            const float a = sact[c * TT + (t + 1)] * k2;
            const float4 xv = *reinterpret_cast<const float4*>(base + (t + 1) * HWS);
            acc.x += a * xv.x; acc.y += a * xv.y; acc.z += a * xv.z; acc.w += a * xv.w;
        }
        og4[v] = acc;
    }
}

extern "C" void kernel_launch(void* const* d_in, const int* in_sizes, int n_in,
                              void* d_out, int out_size, void* d_ws, size_t ws_size,
                              hipStream_t stream) {
    (void)n_in; (void)out_size; (void)d_ws; (void)ws_size;
    const float* x        = (const float*)d_in[0];
    const float* w_g1     = (const float*)d_in[1];
    const float* g1_gamma = (const float*)d_in[2];
    const float* g1_beta  = (const float*)d_in[3];
    const float* g1_mean  = (const float*)d_in[4];
    const float* g1_var   = (const float*)d_in[5];
    const float* w_g2     = (const float*)d_in[6];
    const float* w_l1     = (const float*)d_in[7];
    const float* l1_gamma = (const float*)d_in[8];
    const float* l1_beta  = (const float*)d_in[9];
    const float* l1_mean  = (const float*)d_in[10];
    const float* l1_var   = (const float*)d_in[11];
    const float* w_l2     = (const float*)d_in[12];
    float* out = (float*)d_out;

    const int n_total = in_sizes[0] / SAMPLE;  // 32768
    tam_kernel<<<n_total, 256, 0, stream>>>(
        x, w_g1, g1_gamma, g1_beta, g1_mean, g1_var, w_g2,
        w_l1, l1_gamma, l1_beta, l1_mean, l1_var, w_l2, out);
}